// Round 2
// baseline (203.018 us; speedup 1.0000x reference)
//
#include <hip/hip_runtime.h>
#include <hip/hip_bf16.h>

typedef __bf16 bf16;
typedef __bf16 bf16x4 __attribute__((ext_vector_type(4)));
typedef __bf16 bf16x8 __attribute__((ext_vector_type(8)));
typedef float f32x4 __attribute__((ext_vector_type(4)));
typedef unsigned short u16x4 __attribute__((ext_vector_type(4)));

#define B_ 2
#define S_ 2048
#define H_ 16
#define DH_ 64
#define D_ 1024

// Ordering notes (R2 post-mortem): global_load_lds retires on vmcnt, ds_* on
// lgkmcnt. Two edges MUST be explicit:
//   (1) vmcnt(0) before the barrier that publishes freshly staged LDS tiles.
//   (2) lgkmcnt(0) between a wave's own ds_write and its ds_read of the same
//       bytes (psum broadcast in the epilogue).
#define WAIT_VMCNT0() asm volatile("s_waitcnt vmcnt(0)" ::: "memory")
#define WAIT_LGKM0()  asm volatile("s_waitcnt lgkmcnt(0)" ::: "memory")

// async global->LDS, 16B per lane; LDS dest is wave-uniform base + lane*16
__device__ __forceinline__ void gld_lds16(const bf16* g, bf16* l) {
    __builtin_amdgcn_global_load_lds(
        (__attribute__((address_space(1))) void*)g,
        (__attribute__((address_space(3))) void*)l, 16, 0, 0);
}

// fast RNE float->bf16, no NaN/denorm path (inputs are finite, well-scaled)
__device__ __forceinline__ bf16 f2bf(float x) {
    union { float f; unsigned u; } v; v.f = x;
    unsigned short h = (unsigned short)((v.u + 0x7FFF + ((v.u >> 16) & 1)) >> 16);
    return __builtin_bit_cast(bf16, h);
}

// packed f32x2 -> bf16x2 (RNE), single VALU op (no builtin on gfx950, m240)
__device__ __forceinline__ unsigned cvtpk(float lo, float hi) {
    unsigned r;
    asm("v_cvt_pk_bf16_f32 %0, %1, %2" : "=v"(r) : "v"(lo), "v"(hi));
    return r;
}

// v_permlane32_swap_b32: a.row1 <-> b.row0  =>  a'={a.lo32,b.lo32}, b'={a.hi32,b.hi32}
__device__ __forceinline__ void pl32swap(unsigned &a, unsigned &b) {
    asm("v_permlane32_swap_b32 %0, %1" : "+v"(a), "+v"(b));
}
// v_permlane16_swap_b32: odd 16-rows of a <-> even 16-rows of b
__device__ __forceinline__ void pl16swap(unsigned &a, unsigned &b) {
    asm("v_permlane16_swap_b32 %0, %1" : "+v"(a), "+v"(b));
}

// ---------------------------------------------------------------------------
// Kernel 1: fp32 -> bf16 conversion/packing. (unchanged)
// ---------------------------------------------------------------------------
__global__ __launch_bounds__(256) void cvt_kernel(
    const float* __restrict__ hs,
    const float* __restrict__ Wq, const float* __restrict__ Wk,
    const float* __restrict__ Wv, const float* __restrict__ Wo,
    bf16* __restrict__ hsb, bf16* __restrict__ wqkv, bf16* __restrict__ wob)
{
    int i = (blockIdx.x * 256 + threadIdx.x) * 4;
    const float* src;
    bf16* dst;
    if (i < 4194304) {
        src = hs + i; dst = hsb + i;
    } else if (i < 7340032) {
        int off = i - 4194304;
        int which = off >> 20;           // 0=Wq 1=Wk 2=Wv
        int within = off & 1048575;
        src = (which == 0 ? Wq : which == 1 ? Wk : Wv) + within;
        dst = wqkv + off;
    } else {
        int off = i - 7340032;
        src = Wo + off; dst = wob + off;
    }
    float4 v = *(const float4*)src;
    bf16x4 o = { (bf16)v.x, (bf16)v.y, (bf16)v.z, (bf16)v.w };
    *(bf16x4*)dst = o;
}

// ---------------------------------------------------------------------------
// Kernel 2: QKV projection. (unchanged from R12)
// ---------------------------------------------------------------------------
__global__ __launch_bounds__(256, 3) void gemm_bt(
    const bf16* __restrict__ A, const bf16* __restrict__ Bm,
    const float* __restrict__ b0, const float* __restrict__ b1,
    const float* __restrict__ b2,
    bf16* __restrict__ Qo, bf16* __restrict__ Ko, bf16* __restrict__ Vt)
{
    const int K = 1024;
    __shared__ __attribute__((aligned(16))) bf16 sA[128 * 64];   // 16KB
    __shared__ __attribute__((aligned(16))) bf16 sB[128 * 64];   // 16KB

    int tid = threadIdx.x;
    int wave = tid >> 6, lane = tid & 63;
    int quad = lane >> 4, l16 = lane & 15;
    int m0 = blockIdx.x * 128;
    int n0 = blockIdx.y * 128;
    int wm = (wave & 1) * 64, wn = (wave >> 1) * 64;
    int fs = l16 & 7;                   // read-side swizzle key (row&7 == l16&7)

    f32x4 acc[4][4];
#pragma unroll
    for (int i = 0; i < 4; i++)
#pragma unroll
        for (int j = 0; j < 4; j++) acc[i][j] = (f32x4){0.f, 0.f, 0.f, 0.f};

    for (int k0 = 0; k0 < K; k0 += 64) {
#pragma unroll
        for (int i = 0; i < 4; i++) {
            int c = tid + i * 256;          // 0..1023, 16B each
            int row = c >> 3;               // 8 chunks per 64-elem row
            int kc = ((c & 7) ^ (row & 7)) * 8;   // swizzled source group
            gld_lds16(A + (size_t)(m0 + row) * K + k0 + kc, &sA[c * 8]);
            gld_lds16(Bm + (size_t)(n0 + row) * K + k0 + kc, &sB[c * 8]);
        }
        WAIT_VMCNT0();          // async LDS writes landed before barrier
        __syncthreads();

#pragma unroll
        for (int kp = 0; kp < 2; kp++) {     // two 32-col k-windows
            bf16x8 af[4], bfr[4];
#pragma unroll
            for (int i = 0; i < 4; i++)
                af[i] = *(const bf16x8*)&sA[(wm + i * 16 + l16) * 64 + (((kp * 4 + quad) ^ fs) * 8)];
#pragma unroll
            for (int j = 0; j < 4; j++)
                bfr[j] = *(const bf16x8*)&sB[(wn + j * 16 + l16) * 64 + (((kp * 4 + quad) ^ fs) * 8)];
#pragma unroll
            for (int i = 0; i < 4; i++)
#pragma unroll
                for (int j = 0; j < 4; j++)
                    acc[i][j] = __builtin_amdgcn_mfma_f32_16x16x32_bf16(
                        af[i], bfr[j], acc[i][j], 0, 0, 0);
        }
        __syncthreads();
    }

    // C/D layout: col = lane&15, row = quad*4 + reg  (m89/m91 verified)
    const float QSCALE = 0.125f * 1.44269504088896340736f;  // 1/sqrt(64)*log2(e)
#pragma unroll
    for (int j = 0; j < 4; j++) {
        int n = n0 + wn + j * 16 + l16;
        int region = n >> 10;            // block-uniform (n0 128-aligned)
        int nn = n & 1023;
        int h = nn >> 6, d = nn & 63;
        float bias = (region == 0 ? b0 : region == 1 ? b1 : b2)[nn];
#pragma unroll
        for (int i = 0; i < 4; i++) {
            int mb = m0 + wm + i * 16 + quad * 4;     // 4-aligned, no 2048-cross
            int b = mb >> 11, s = mb & 2047;
            int bh = b * H_ + h;
            if (region == 2) {
                // packed V^T store: 4 consecutive s at fixed d (b64)
                bf16x4 pk = { f2bf(acc[i][j][0] + bias), f2bf(acc[i][j][1] + bias),
                              f2bf(acc[i][j][2] + bias), f2bf(acc[i][j][3] + bias) };
                *(bf16x4*)&Vt[((size_t)bh * DH_ + d) * S_ + s] = pk;
            } else {
#pragma unroll
                for (int r = 0; r < 4; r++) {
                    float v = acc[i][j][r] + bias;
                    if (region == 0)
                        Qo[((size_t)bh * S_ + s + r) * DH_ + d] = f2bf(v * QSCALE);
                    else
                        Ko[((size_t)bh * S_ + s + r) * DH_ + d] = f2bf(v);
                }
            }
        }
    }
}

// ---------------------------------------------------------------------------
// Kernel 4 (R12, unchanged): out = attn @ Wo^T + bo. 128m x 64n tile, BK=64.
// ---------------------------------------------------------------------------
__global__ __launch_bounds__(256, 2) void gemm_out(
    const bf16* __restrict__ A, const bf16* __restrict__ Bm,
    const float* __restrict__ bias0, float* __restrict__ Co)
{
    const int K = 1024;
    __shared__ __attribute__((aligned(16))) bf16 sA[128 * 64];   // 16KB
    __shared__ __attribute__((aligned(16))) bf16 sB[64 * 64];    // 8KB

    int tid = threadIdx.x;
    int wave = tid >> 6, lane = tid & 63;
    int quad = lane >> 4, l16 = lane & 15;
    int m0 = blockIdx.x * 128;
    int n0 = blockIdx.y * 64;
    int wm = (wave & 1) * 64, wn = (wave >> 1) * 32;
    int fs = l16 & 7;

    f32x4 acc[4][2];
#pragma unroll
    for (int i = 0; i < 4; i++)
#pragma unroll
        for (int j = 0; j < 2; j++) acc[i][j] = (f32x4){0.f, 0.f, 0.f, 0.f};

    for (int k0 = 0; k0 < K; k0 += 64) {
#pragma unroll
        for (int i = 0; i < 4; i++) {        // A: 1024 chunks
            int c = tid + i * 256;
            int row = c >> 3;
            int kc = ((c & 7) ^ (row & 7)) * 8;
            gld_lds16(A + (size_t)(m0 + row) * K + k0 + kc, &sA[c * 8]);
        }
#pragma unroll
        for (int i = 0; i < 2; i++) {        // B: 512 chunks
            int c = tid + i * 256;
            int row = c >> 3;
            int kc = ((c & 7) ^ (row & 7)) * 8;
            gld_lds16(Bm + (size_t)(n0 + row) * K + k0 + kc, &sB[c * 8]);
        }
        WAIT_VMCNT0();
        __syncthreads();

#pragma unroll
        for (int kp = 0; kp < 2; kp++) {
            bf16x8 af[4], bfr[2];
#pragma unroll
            for (int i = 0; i < 4; i++)
                af[i] = *(const bf16x8*)&sA[(wm + i * 16 + l16) * 64 + (((kp * 4 + quad) ^ fs) * 8)];
#pragma unroll
            for (int j = 0; j < 2; j++)
                bfr[j] = *(const bf16x8*)&sB[(wn + j * 16 + l16) * 64 + (((kp * 4 + quad) ^ fs) * 8)];
#pragma unroll
            for (int i = 0; i < 4; i++)
#pragma unroll
                for (int j = 0; j < 2; j++)
                    acc[i][j] = __builtin_amdgcn_mfma_f32_16x16x32_bf16(
                        af[i], bfr[j], acc[i][j], 0, 0, 0);
        }
        __syncthreads();
    }

#pragma unroll
    for (int j = 0; j < 2; j++) {
        int n = n0 + wn + j * 16 + l16;
        float bias = bias0[n];
#pragma unroll
        for (int i = 0; i < 4; i++)
#pragma unroll
            for (int r = 0; r < 4; r++) {
                int m = m0 + wm + i * 16 + quad * 4 + r;
                Co[(size_t)m * D_ + n] = acc[i][j][r] + bias;
            }
    }
}

// ---------------------------------------------------------------------------
// Kernel 3 (R14): flash attention, q-split 8-wave, dbuf staging, C-init mask.
// Changes vs R13:
//   * 8 waves x 16 q each (q-tile 128), every wave iterates ALL 128 keys/iter.
//     NO cross-wave O reduction (was: 16KBx2 LDS round-trip + 2 barriers +
//     waves 0-1 doing all the finish work). psum closes with 2 shfl_xor + a
//     512B same-wave LDS broadcast. All 8 waves store output.
//   * mask-add rides the QK^T MFMA C-input (per-key == per-C-row): deletes
//     16 v_add per 32-key group and shortens the exp2 dep chain.
//   * LDS double-buffer: stage tile t+1 before computing tile t; ONE
//     vmcnt(0)+barrier per tile (was 2). 68.6KB LDS -> still 2 blocks/CU
//     (grid 512 = 2/CU is the cap anyway), so dbuf costs no occupancy.
//   * grid (16,32) = 512 blocks: half the per-CU staging instructions and
//     half the logical K/V re-fetch vs R13's 1024 blocks.
// ---------------------------------------------------------------------------
__global__ __launch_bounds__(512, 4) void attn_kernel(
    const bf16* __restrict__ Q, const bf16* __restrict__ Kg,
    const bf16* __restrict__ Vt, const int* __restrict__ mask,
    bf16* __restrict__ Og)
{
    __shared__ __attribute__((aligned(16))) bf16 sK[2][128 * 64];     // [key][dh] 2x16KB
    __shared__ __attribute__((aligned(16))) bf16 sV[2][64 * 128];     // [d][key]  2x16KB
    __shared__ __attribute__((aligned(16))) unsigned short sMadd[S_]; // 4KB
    __shared__ float sPsumW[128];                                     // 8 waves x 16 q

    int tid = threadIdx.x;
    int wave = tid >> 6, lane = tid & 63;
    int quad = lane >> 4, l16 = lane & 15;
    int bh = blockIdx.y;
    int b = bh >> 4;
    int q0 = blockIdx.x * 128;
    int f8 = l16 & 7;                          // sK read swizzle key

    const bf16* Qb = Q + (size_t)bh * S_ * DH_;
    const bf16* Kb = Kg + (size_t)bh * S_ * DH_;
    const bf16* Vb = Vt + (size_t)bh * DH_ * S_;

    // expand mask row once per block: 1 -> 0x0000 (0.0f), 0 -> 0xF149 (-9.96e29)
    // 2048 entries / 512 threads = 4 each.
    {
        int4 m0 = *(const int4*)&mask[b * S_ + tid * 4];
        u16x4 e0 = { (unsigned short)(m0.x ? 0 : 0xF149),
                     (unsigned short)(m0.y ? 0 : 0xF149),
                     (unsigned short)(m0.z ? 0 : 0xF149),
                     (unsigned short)(m0.w ? 0 : 0xF149) };
        *(u16x4*)&sMadd[tid * 4] = e0;
    }

    // Q fragments: wave owns q rows [q0+wave*16, +16)
    // (B-operand; layout n=lane&15, k=quad*8+j)
    bf16x8 aq[2];
    {
        int qrow = q0 + wave * 16 + l16;
        aq[0] = *(const bf16x8*)&Qb[(size_t)qrow * DH_ + quad * 8];
        aq[1] = *(const bf16x8*)&Qb[(size_t)qrow * DH_ + 32 + quad * 8];
    }

    f32x4 o[4];                          // o[dt], C row=q(quad*4+r), col=d
#pragma unroll
    for (int j = 0; j < 4; j++) o[j] = (f32x4){0.f, 0.f, 0.f, 0.f};
    float psum = 0.f;                    // per lane: q=l16, keys=quad*4+r groups

    // stage tile 0 into buf 0: K 1024 chunks + V 1024 chunks, 4 per thread
#pragma unroll
    for (int i = 0; i < 2; i++) {
        int c = tid + i * 512;
        int row = c >> 3;
        int g = (c & 7) ^ (row & 7);
        gld_lds16(&Kb[(size_t)row * DH_ + g * 8], &sK[0][c * 8]);
    }
#pragma unroll
    for (int i = 0; i < 2; i++) {
        int cv = tid + i * 512;
        int row = cv >> 4;
        int g = (cv & 15) ^ (row & 15);
        gld_lds16(&Vb[(size_t)row * S_ + g * 8], &sV[0][cv * 8]);
    }
    WAIT_VMCNT0();
    __syncthreads();

    for (int kti = 0; kti < 16; kti++) {
        int kt = kti * 128;
        int cur = kti & 1;

        // issue next tile's staging into the other buffer (overlaps compute)
        if (kti < 15) {
            int ktn = kt + 128;
#pragma unroll
            for (int i = 0; i < 2; i++) {
                int c = tid + i * 512;
                int row = c >> 3;
                int g = (c & 7) ^ (row & 7);
                gld_lds16(&Kb[(size_t)(ktn + row) * DH_ + g * 8], &sK[cur ^ 1][c * 8]);
            }
#pragma unroll
            for (int i = 0; i < 2; i++) {
                int cv = tid + i * 512;
                int row = cv >> 4;
                int g = (cv & 15) ^ (row & 15);
                gld_lds16(&Vb[(size_t)row * S_ + ktn + g * 8], &sV[cur ^ 1][cv * 8]);
            }
        }

        const bf16* sKc = sK[cur];
        const bf16* sVc = sV[cur];

#pragma unroll
        for (int ks = 0; ks < 4; ks++) {         // 32 keys per group
            unsigned w01[2], w23[2];             // [m]: keys q'*4+{0,1}/{2,3}
#pragma unroll
            for (int m = 0; m < 2; m++) {
                int keyrow = ks * 32 + m * 16;
                bf16x8 ak0 = *(const bf16x8*)&sKc[(keyrow + l16) * 64 + ((quad ^ f8) * 8)];
                bf16x8 ak1 = *(const bf16x8*)&sKc[(keyrow + l16) * 64 + (((quad + 4) ^ f8) * 8)];
                u16x4 mm = *(const u16x4*)&sMadd[kt + keyrow + quad * 4];
                // mask-add as MFMA C-init (per key == per C row)
                f32x4 c;
                c[0] = __builtin_bit_cast(float, (unsigned)mm.x << 16);
                c[1] = __builtin_bit_cast(float, (unsigned)mm.y << 16);
                c[2] = __builtin_bit_cast(float, (unsigned)mm.z << 16);
                c[3] = __builtin_bit_cast(float, (unsigned)mm.w << 16);
                c = __builtin_amdgcn_mfma_f32_16x16x32_bf16(ak0, aq[0], c, 0, 0, 0);
                c = __builtin_amdgcn_mfma_f32_16x16x32_bf16(ak1, aq[1], c, 0, 0, 0);
                float p0 = __builtin_amdgcn_exp2f(c[0]);
                float p1 = __builtin_amdgcn_exp2f(c[1]);
                float p2 = __builtin_amdgcn_exp2f(c[2]);
                float p3 = __builtin_amdgcn_exp2f(c[3]);
                psum += (p0 + p1) + (p2 + p3);
                w01[m] = cvtpk(p0, p1);
                w23[m] = cvtpk(p2, p3);
            }

            // in-register remap (R13-verified): (W[m0],W[m1]) -> PV A-frag words
            unsigned r0 = w01[0], r2 = w01[1];
            pl32swap(r0, r2); pl16swap(r0, r2);            // -> word0, word2
            unsigned r1 = w23[0], r3 = w23[1];
            pl32swap(r1, r3); pl16swap(r1, r3);            // -> word1, word3
            union { unsigned u[4]; bf16x8 v; } U;
            U.u[0] = r0; U.u[1] = r1; U.u[2] = r2; U.u[3] = r3;
            bf16x8 ap = U.v;

            // O += P @ V (A=P[q][k32] in regs, B=V^T[d][k32])
#pragma unroll
            for (int dt = 0; dt < 4; dt++) {
                bf16x8 bv = *(const bf16x8*)&sVc[(dt * 16 + l16) * 128 + (((ks * 4 + quad) ^ l16) * 8)];
                o[dt] = __builtin_amdgcn_mfma_f32_16x16x32_bf16(ap, bv, o[dt], 0, 0, 0);
            }
        }

        if (kti < 15) {
            WAIT_VMCNT0();      // next-tile staging landed
            __syncthreads();    // publishes buf^1; all reads of buf done
        }
    }

    // psum: reduce over quads (key groups) -> every lane holds full sum for q=l16
    psum += __shfl_xor(psum, 16);
    psum += __shfl_xor(psum, 32);

    // broadcast to (quad,reg) q-indexing via same-wave LDS (512B total)
    sPsumW[wave * 16 + l16] = psum;
    WAIT_LGKM0();   // same-wave write -> read
    float4 ps = *(const float4*)&sPsumW[wave * 16 + quad * 4];
    float rcp[4] = { 1.f / ps.x, 1.f / ps.y, 1.f / ps.z, 1.f / ps.w };

    int h = bh & 15;
#pragma unroll
    for (int r = 0; r < 4; r++) {
        int s = q0 + wave * 16 + quad * 4 + r;
#pragma unroll
        for (int dt = 0; dt < 4; dt++) {
            int d = dt * 16 + l16;
            Og[((size_t)(b * S_ + s)) * D_ + h * 64 + d] = f2bf(o[dt][r] * rcp[r]);
        }
    }
}

// ---------------------------------------------------------------------------
extern "C" void kernel_launch(void* const* d_in, const int* in_sizes, int n_in,
                              void* d_out, int out_size, void* d_ws, size_t ws_size,
                              hipStream_t stream) {
    const float* hs = (const float*)d_in[0];
    const int* mask = (const int*)d_in[1];
    const float* Wq = (const float*)d_in[2];
    const float* bq = (const float*)d_in[3];
    const float* Wk = (const float*)d_in[4];
    const float* bk = (const float*)d_in[5];
    const float* Wv = (const float*)d_in[6];
    const float* bv = (const float*)d_in[7];
    const float* Wo = (const float*)d_in[8];
    const float* bo = (const float*)d_in[9];
    float* out = (float*)d_out;

    char* ws = (char*)d_ws;
    bf16* hsb  = (bf16*)(ws);                          // 8 MB (4096x1024)
    bf16* wqkv = (bf16*)(ws + ((size_t)8 << 20));      // 6 MB (3072x1024)
    bf16* wob  = (bf16*)(ws + ((size_t)14 << 20));     // 2 MB (1024x1024)
    bf16* Qw   = (bf16*)(ws + ((size_t)16 << 20));     // 8 MB (b,h,s,d)
    bf16* Kw   = (bf16*)(ws + ((size_t)24 << 20));     // 8 MB (b,h,s,d)
    bf16* Vtw  = (bf16*)(ws + ((size_t)32 << 20));     // 8 MB (b,h,d,s)
    bf16* attn = (bf16*)(ws + ((size_t)40 << 20));     // 8 MB (b,s,h*64+d)

    cvt_kernel<<<8192, 256, 0, stream>>>(hs, Wq, Wk, Wv, Wo, hsb, wqkv, wob);
    gemm_bt<<<dim3(32, 24), 256, 0, stream>>>(hsb, wqkv, bq, bk, bv,
                                              Qw, Kw, Vtw);
    attn_kernel<<<dim3(16, 32), 512, 0, stream>>>(Qw, Kw, Vtw, mask, attn);
    gemm_out<<<dim3(32, 16), 256, 0, stream>>>(attn, wob, bo, out);
}

// Round 3
// 187.135 us; speedup vs baseline: 1.0849x; 1.0849x over previous
//
#include <hip/hip_runtime.h>
#include <hip/hip_bf16.h>

typedef __bf16 bf16;
typedef __bf16 bf16x4 __attribute__((ext_vector_type(4)));
typedef __bf16 bf16x8 __attribute__((ext_vector_type(8)));
typedef float f32x4 __attribute__((ext_vector_type(4)));
typedef unsigned short u16x4 __attribute__((ext_vector_type(4)));

#define B_ 2
#define S_ 2048
#define H_ 16
#define DH_ 64
#define D_ 1024

// Ordering notes (R2 post-mortem): global_load_lds retires on vmcnt, ds_* on
// lgkmcnt. Two edges MUST be explicit:
//   (1) vmcnt(0) before the barrier that publishes freshly staged LDS tiles.
//   (2) lgkmcnt(0) between a wave's own ds_write and its ds_read of the same
//       bytes.
// R6+R8+R14: explicit double-buffering regressed three times — implicit TLP
// at 4 blocks/CU (16 waves) hides staging latency better than dbuf at 2
// blocks/CU. R14 also showed q-split doubles per-wave LDS reads: keep
// key-split.
#define WAIT_VMCNT0() asm volatile("s_waitcnt vmcnt(0)" ::: "memory")
#define WAIT_LGKM0()  asm volatile("s_waitcnt lgkmcnt(0)" ::: "memory")

// async global->LDS, 16B per lane; LDS dest is wave-uniform base + lane*16
__device__ __forceinline__ void gld_lds16(const bf16* g, bf16* l) {
    __builtin_amdgcn_global_load_lds(
        (__attribute__((address_space(1))) void*)g,
        (__attribute__((address_space(3))) void*)l, 16, 0, 0);
}

// fast RNE float->bf16, no NaN/denorm path (inputs are finite, well-scaled)
__device__ __forceinline__ bf16 f2bf(float x) {
    union { float f; unsigned u; } v; v.f = x;
    unsigned short h = (unsigned short)((v.u + 0x7FFF + ((v.u >> 16) & 1)) >> 16);
    return __builtin_bit_cast(bf16, h);
}

// packed f32x2 -> bf16x2 (RNE), single VALU op (no builtin on gfx950, m240)
__device__ __forceinline__ unsigned cvtpk(float lo, float hi) {
    unsigned r;
    asm("v_cvt_pk_bf16_f32 %0, %1, %2" : "=v"(r) : "v"(lo), "v"(hi));
    return r;
}

// v_permlane32_swap_b32: a.row1 <-> b.row0  =>  a'={a.lo32,b.lo32}, b'={a.hi32,b.hi32}
__device__ __forceinline__ void pl32swap(unsigned &a, unsigned &b) {
    asm("v_permlane32_swap_b32 %0, %1" : "+v"(a), "+v"(b));
}
// v_permlane16_swap_b32: odd 16-rows of a <-> even 16-rows of b
__device__ __forceinline__ void pl16swap(unsigned &a, unsigned &b) {
    asm("v_permlane16_swap_b32 %0, %1" : "+v"(a), "+v"(b));
}

// ---------------------------------------------------------------------------
// Kernel 1: fp32 -> bf16 conversion/packing. (unchanged)
// ---------------------------------------------------------------------------
__global__ __launch_bounds__(256) void cvt_kernel(
    const float* __restrict__ hs,
    const float* __restrict__ Wq, const float* __restrict__ Wk,
    const float* __restrict__ Wv, const float* __restrict__ Wo,
    bf16* __restrict__ hsb, bf16* __restrict__ wqkv, bf16* __restrict__ wob)
{
    int i = (blockIdx.x * 256 + threadIdx.x) * 4;
    const float* src;
    bf16* dst;
    if (i < 4194304) {
        src = hs + i; dst = hsb + i;
    } else if (i < 7340032) {
        int off = i - 4194304;
        int which = off >> 20;           // 0=Wq 1=Wk 2=Wv
        int within = off & 1048575;
        src = (which == 0 ? Wq : which == 1 ? Wk : Wv) + within;
        dst = wqkv + off;
    } else {
        int off = i - 7340032;
        src = Wo + off; dst = wob + off;
    }
    float4 v = *(const float4*)src;
    bf16x4 o = { (bf16)v.x, (bf16)v.y, (bf16)v.z, (bf16)v.w };
    *(bf16x4*)dst = o;
}

// ---------------------------------------------------------------------------
// Kernel 2: QKV projection. (unchanged from R12)
// ---------------------------------------------------------------------------
__global__ __launch_bounds__(256, 3) void gemm_bt(
    const bf16* __restrict__ A, const bf16* __restrict__ Bm,
    const float* __restrict__ b0, const float* __restrict__ b1,
    const float* __restrict__ b2,
    bf16* __restrict__ Qo, bf16* __restrict__ Ko, bf16* __restrict__ Vt)
{
    const int K = 1024;
    __shared__ __attribute__((aligned(16))) bf16 sA[128 * 64];   // 16KB
    __shared__ __attribute__((aligned(16))) bf16 sB[128 * 64];   // 16KB

    int tid = threadIdx.x;
    int wave = tid >> 6, lane = tid & 63;
    int quad = lane >> 4, l16 = lane & 15;
    int m0 = blockIdx.x * 128;
    int n0 = blockIdx.y * 128;
    int wm = (wave & 1) * 64, wn = (wave >> 1) * 64;
    int fs = l16 & 7;                   // read-side swizzle key (row&7 == l16&7)

    f32x4 acc[4][4];
#pragma unroll
    for (int i = 0; i < 4; i++)
#pragma unroll
        for (int j = 0; j < 4; j++) acc[i][j] = (f32x4){0.f, 0.f, 0.f, 0.f};

    for (int k0 = 0; k0 < K; k0 += 64) {
#pragma unroll
        for (int i = 0; i < 4; i++) {
            int c = tid + i * 256;          // 0..1023, 16B each
            int row = c >> 3;               // 8 chunks per 64-elem row
            int kc = ((c & 7) ^ (row & 7)) * 8;   // swizzled source group
            gld_lds16(A + (size_t)(m0 + row) * K + k0 + kc, &sA[c * 8]);
            gld_lds16(Bm + (size_t)(n0 + row) * K + k0 + kc, &sB[c * 8]);
        }
        WAIT_VMCNT0();          // async LDS writes landed before barrier
        __syncthreads();

#pragma unroll
        for (int kp = 0; kp < 2; kp++) {     // two 32-col k-windows
            bf16x8 af[4], bfr[4];
#pragma unroll
            for (int i = 0; i < 4; i++)
                af[i] = *(const bf16x8*)&sA[(wm + i * 16 + l16) * 64 + (((kp * 4 + quad) ^ fs) * 8)];
#pragma unroll
            for (int j = 0; j < 4; j++)
                bfr[j] = *(const bf16x8*)&sB[(wn + j * 16 + l16) * 64 + (((kp * 4 + quad) ^ fs) * 8)];
#pragma unroll
            for (int i = 0; i < 4; i++)
#pragma unroll
                for (int j = 0; j < 4; j++)
                    acc[i][j] = __builtin_amdgcn_mfma_f32_16x16x32_bf16(
                        af[i], bfr[j], acc[i][j], 0, 0, 0);
        }
        __syncthreads();
    }

    // C/D layout: col = lane&15, row = quad*4 + reg  (m89/m91 verified)
    const float QSCALE = 0.125f * 1.44269504088896340736f;  // 1/sqrt(64)*log2(e)
#pragma unroll
    for (int j = 0; j < 4; j++) {
        int n = n0 + wn + j * 16 + l16;
        int region = n >> 10;            // block-uniform (n0 128-aligned)
        int nn = n & 1023;
        int h = nn >> 6, d = nn & 63;
        float bias = (region == 0 ? b0 : region == 1 ? b1 : b2)[nn];
#pragma unroll
        for (int i = 0; i < 4; i++) {
            int mb = m0 + wm + i * 16 + quad * 4;     // 4-aligned, no 2048-cross
            int b = mb >> 11, s = mb & 2047;
            int bh = b * H_ + h;
            if (region == 2) {
                // packed V^T store: 4 consecutive s at fixed d (b64)
                bf16x4 pk = { f2bf(acc[i][j][0] + bias), f2bf(acc[i][j][1] + bias),
                              f2bf(acc[i][j][2] + bias), f2bf(acc[i][j][3] + bias) };
                *(bf16x4*)&Vt[((size_t)bh * DH_ + d) * S_ + s] = pk;
            } else {
#pragma unroll
                for (int r = 0; r < 4; r++) {
                    float v = acc[i][j][r] + bias;
                    if (region == 0)
                        Qo[((size_t)bh * S_ + s + r) * DH_ + d] = f2bf(v * QSCALE);
                    else
                        Ko[((size_t)bh * S_ + s + r) * DH_ + d] = f2bf(v);
                }
            }
        }
    }
}

// ---------------------------------------------------------------------------
// Kernel 4 (R12, unchanged): out = attn @ Wo^T + bo. 128m x 64n tile, BK=64.
// ---------------------------------------------------------------------------
__global__ __launch_bounds__(256, 2) void gemm_out(
    const bf16* __restrict__ A, const bf16* __restrict__ Bm,
    const float* __restrict__ bias0, float* __restrict__ Co)
{
    const int K = 1024;
    __shared__ __attribute__((aligned(16))) bf16 sA[128 * 64];   // 16KB
    __shared__ __attribute__((aligned(16))) bf16 sB[64 * 64];    // 8KB

    int tid = threadIdx.x;
    int wave = tid >> 6, lane = tid & 63;
    int quad = lane >> 4, l16 = lane & 15;
    int m0 = blockIdx.x * 128;
    int n0 = blockIdx.y * 64;
    int wm = (wave & 1) * 64, wn = (wave >> 1) * 32;
    int fs = l16 & 7;

    f32x4 acc[4][2];
#pragma unroll
    for (int i = 0; i < 4; i++)
#pragma unroll
        for (int j = 0; j < 2; j++) acc[i][j] = (f32x4){0.f, 0.f, 0.f, 0.f};

    for (int k0 = 0; k0 < K; k0 += 64) {
#pragma unroll
        for (int i = 0; i < 4; i++) {        // A: 1024 chunks
            int c = tid + i * 256;
            int row = c >> 3;
            int kc = ((c & 7) ^ (row & 7)) * 8;
            gld_lds16(A + (size_t)(m0 + row) * K + k0 + kc, &sA[c * 8]);
        }
#pragma unroll
        for (int i = 0; i < 2; i++) {        // B: 512 chunks
            int c = tid + i * 256;
            int row = c >> 3;
            int kc = ((c & 7) ^ (row & 7)) * 8;
            gld_lds16(Bm + (size_t)(n0 + row) * K + k0 + kc, &sB[c * 8]);
        }
        WAIT_VMCNT0();
        __syncthreads();

#pragma unroll
        for (int kp = 0; kp < 2; kp++) {
            bf16x8 af[4], bfr[2];
#pragma unroll
            for (int i = 0; i < 4; i++)
                af[i] = *(const bf16x8*)&sA[(wm + i * 16 + l16) * 64 + (((kp * 4 + quad) ^ fs) * 8)];
#pragma unroll
            for (int j = 0; j < 2; j++)
                bfr[j] = *(const bf16x8*)&sB[(wn + j * 16 + l16) * 64 + (((kp * 4 + quad) ^ fs) * 8)];
#pragma unroll
            for (int i = 0; i < 4; i++)
#pragma unroll
                for (int j = 0; j < 2; j++)
                    acc[i][j] = __builtin_amdgcn_mfma_f32_16x16x32_bf16(
                        af[i], bfr[j], acc[i][j], 0, 0, 0);
        }
        __syncthreads();
    }

#pragma unroll
    for (int j = 0; j < 2; j++) {
        int n = n0 + wn + j * 16 + l16;
        float bias = bias0[n];
#pragma unroll
        for (int i = 0; i < 4; i++)
#pragma unroll
            for (int r = 0; r < 4; r++) {
                int m = m0 + wm + i * 16 + quad * 4 + r;
                Co[(size_t)m * D_ + n] = acc[i][j][r] + bias;
            }
    }
}

// ---------------------------------------------------------------------------
// Kernel 3 (R15): flash attention = R13 structure (4 waves, key-split,
// single-buffer, 4 blocks/CU) + two VALU cuts:
//   * mask-add rides the QK^T MFMA C-input (chain-shortening; R14-verified
//     numerics).
//   * psum via ones-column MFMA: one extra PV-shaped MFMA per (pass,qt) with
//     B = all-ones replaces 32 v_add/tile + both shfl_xor + the sPsum LDS
//     broadcast. osum C-layout (row=quad*4+r=q) matches the store indexing
//     exactly.
// R14 lessons applied: NO dbuf, NO q-split (doubles LDS reads), 256 threads.
// ---------------------------------------------------------------------------
__global__ __launch_bounds__(256, 4) void attn_kernel(
    const bf16* __restrict__ Q, const bf16* __restrict__ Kg,
    const bf16* __restrict__ Vt, const int* __restrict__ mask,
    bf16* __restrict__ Og)
{
    __shared__ __attribute__((aligned(16))) bf16 sK[128 * 64];        // [key][dh] 16KB
    __shared__ __attribute__((aligned(16))) bf16 sV[64 * 128];        // [d][key] 16KB
    __shared__ __attribute__((aligned(16))) unsigned short sMadd[S_]; // 4KB

    int tid = threadIdx.x;
    int wave = tid >> 6, lane = tid & 63;
    int quad = lane >> 4, l16 = lane & 15;
    int bh = blockIdx.y;
    int b = bh >> 4;
    int q0 = blockIdx.x * 64;
    int f8 = l16 & 7;                          // sK read swizzle key
    int qh = wave & 1;                         // q-half (0/1), 32 q each
    int kh = wave >> 1;                        // key-half (0/1), 64 keys/iter each

    const bf16* Qb = Q + (size_t)bh * S_ * DH_;
    const bf16* Kb = Kg + (size_t)bh * S_ * DH_;
    const bf16* Vb = Vt + (size_t)bh * DH_ * S_;

    // expand mask row once per block: 1 -> 0x0000 (0.0f), 0 -> 0xF149 (-9.96e29)
    // 2048 entries / 256 threads = 8 each; visibility via first loop barrier.
    {
        int base = b * S_ + tid * 8;
        int4 m0 = *(const int4*)&mask[base];
        int4 m1 = *(const int4*)&mask[base + 4];
        u16x4 e0 = { (unsigned short)(m0.x ? 0 : 0xF149),
                     (unsigned short)(m0.y ? 0 : 0xF149),
                     (unsigned short)(m0.z ? 0 : 0xF149),
                     (unsigned short)(m0.w ? 0 : 0xF149) };
        u16x4 e1 = { (unsigned short)(m1.x ? 0 : 0xF149),
                     (unsigned short)(m1.y ? 0 : 0xF149),
                     (unsigned short)(m1.z ? 0 : 0xF149),
                     (unsigned short)(m1.w ? 0 : 0xF149) };
        *(u16x4*)&sMadd[tid * 8] = e0;
        *(u16x4*)&sMadd[tid * 8 + 4] = e1;
    }

    // Q fragments for 2 q-tiles (B-operand; layout n=lane&15, k=quad*8+j)
    bf16x8 aq[2][2];
#pragma unroll
    for (int qt = 0; qt < 2; qt++) {
        int qrow = q0 + qh * 32 + qt * 16 + l16;
        aq[qt][0] = *(const bf16x8*)&Qb[(size_t)qrow * DH_ + quad * 8];
        aq[qt][1] = *(const bf16x8*)&Qb[(size_t)qrow * DH_ + 32 + quad * 8];
    }

    // ones B-fragment for row-sum MFMA (B rows n all see ones over k)
    const bf16 oneb = __builtin_bit_cast(bf16, (unsigned short)0x3F80);
    const bf16x8 ones = { oneb, oneb, oneb, oneb, oneb, oneb, oneb, oneb };

    f32x4 o[2][4];                       // o[qt][dt], C row=q, col=d
    f32x4 osum[2];                       // row-sums of P, C row=q (col dup'd)
#pragma unroll
    for (int i = 0; i < 2; i++) {
#pragma unroll
        for (int j = 0; j < 4; j++) o[i][j] = (f32x4){0.f, 0.f, 0.f, 0.f};
        osum[i] = (f32x4){0.f, 0.f, 0.f, 0.f};
    }

    for (int kt = 0; kt < S_; kt += 128) {
        // stage K[128k][64dh] + V^T[64d][128k]; source-col swizzled so the
        // lane-contiguous DMA dest gives conflict-free fragment reads.
#pragma unroll
        for (int i = 0; i < 8; i++) {
            int c = tid + i * 256;            // 0..2047
            if (c < 1024) {                   // K chunk: row=c>>3, group=c&7
                int row = c >> 3;
                int g = (c & 7) ^ (row & 7);
                gld_lds16(&Kb[(size_t)(kt + row) * DH_ + g * 8], &sK[c * 8]);
            } else {                          // V chunk: row=(c-1024)>>4, group=&15
                int cv = c - 1024;
                int row = cv >> 4;
                int g = (cv & 15) ^ (row & 15);
                gld_lds16(&Vb[(size_t)row * S_ + kt + g * 8], &sV[cv * 8]);
            }
        }
        WAIT_VMCNT0();
        __syncthreads();

#pragma unroll
        for (int pass = 0; pass < 2; pass++) {   // 32 keys per pass
            // --- S^T = K @ Q^T, P = exp2(S + maskadd), kept in registers ---
            unsigned w01[2][2], w23[2][2];       // [qt][mtl]: keys q'*4+{0,1}/{2,3}
#pragma unroll
            for (int mtl = 0; mtl < 2; mtl++) {
                int keyrow = kh * 64 + pass * 32 + mtl * 16;   // wave-local tile base
                bf16x8 ak0 = *(const bf16x8*)&sK[(keyrow + l16) * 64 + ((quad ^ f8) * 8)];
                bf16x8 ak1 = *(const bf16x8*)&sK[(keyrow + l16) * 64 + (((quad + 4) ^ f8) * 8)];
                u16x4 mm = *(const u16x4*)&sMadd[kt + keyrow + quad * 4];
                // mask-add as MFMA C-init (per key == per C row)
                f32x4 cinit;
                cinit[0] = __builtin_bit_cast(float, (unsigned)mm.x << 16);
                cinit[1] = __builtin_bit_cast(float, (unsigned)mm.y << 16);
                cinit[2] = __builtin_bit_cast(float, (unsigned)mm.z << 16);
                cinit[3] = __builtin_bit_cast(float, (unsigned)mm.w << 16);
#pragma unroll
                for (int qt = 0; qt < 2; qt++) {
                    f32x4 c = cinit;
                    c = __builtin_amdgcn_mfma_f32_16x16x32_bf16(ak0, aq[qt][0], c, 0, 0, 0);
                    c = __builtin_amdgcn_mfma_f32_16x16x32_bf16(ak1, aq[qt][1], c, 0, 0, 0);
                    float p0 = __builtin_amdgcn_exp2f(c[0]);
                    float p1 = __builtin_amdgcn_exp2f(c[1]);
                    float p2 = __builtin_amdgcn_exp2f(c[2]);
                    float p3 = __builtin_amdgcn_exp2f(c[3]);
                    w01[qt][mtl] = cvtpk(p0, p1);
                    w23[qt][mtl] = cvtpk(p2, p3);
                }
            }

            // --- in-register remap (R13-verified): -> PV A-frag words ---
            bf16x8 ap[2];
#pragma unroll
            for (int qt = 0; qt < 2; qt++) {
                unsigned r0 = w01[qt][0], r2 = w01[qt][1];     // j=0 pair
                pl32swap(r0, r2); pl16swap(r0, r2);            // -> word0, word2
                unsigned r1 = w23[qt][0], r3 = w23[qt][1];     // j=1 pair
                pl32swap(r1, r3); pl16swap(r1, r3);            // -> word1, word3
                union { unsigned u[4]; bf16x8 v; } U;
                U.u[0] = r0; U.u[1] = r1; U.u[2] = r2; U.u[3] = r3;
                ap[qt] = U.v;
                // row-sums: osum[qt] += P @ ones  (replaces scalar psum adds)
                osum[qt] = __builtin_amdgcn_mfma_f32_16x16x32_bf16(ap[qt], ones, osum[qt], 0, 0, 0);
            }

            // --- O += P @ V (A=P[q][k32] in regs, B=V^T[d][k32]) ---
#pragma unroll
            for (int dt = 0; dt < 4; dt++) {
                int g = (kh * 8 + pass * 4 + quad) ^ l16;      // sV group slot
                bf16x8 bv = *(const bf16x8*)&sV[(dt * 16 + l16) * 128 + g * 8];
#pragma unroll
                for (int qt = 0; qt < 2; qt++)
                    o[qt][dt] = __builtin_amdgcn_mfma_f32_16x16x32_bf16(ap[qt], bv, o[qt][dt], 0, 0, 0);
            }
        }
        __syncthreads();   // all fragment reads done before next staging
    }

    // cross-wave reduction: waves 2,3 (key-half 1) hand partials (o + osum)
    // to waves 0,1. Slots 0..7 = o[qt][dt], slots 8..9 = osum[qt].
    float* sRed = (wave == 2) ? (float*)sK : (float*)sV;   // 16KB each, 10KB used
    if (wave >= 2) {
#pragma unroll
        for (int qt = 0; qt < 2; qt++) {
#pragma unroll
            for (int dt = 0; dt < 4; dt++)
                *(f32x4*)&sRed[((qt * 4 + dt) * 64 + lane) * 4] = o[qt][dt];
            *(f32x4*)&sRed[((8 + qt) * 64 + lane) * 4] = osum[qt];
        }
    }
    __syncthreads();
    if (wave < 2) {
        float* src = (wave == 0) ? (float*)sK : (float*)sV;
#pragma unroll
        for (int qt = 0; qt < 2; qt++) {
#pragma unroll
            for (int dt = 0; dt < 4; dt++)
                o[qt][dt] += *(const f32x4*)&src[((qt * 4 + dt) * 64 + lane) * 4];
            osum[qt] += *(const f32x4*)&src[((8 + qt) * 64 + lane) * 4];
        }
        int h = bh & 15;
#pragma unroll
        for (int qt = 0; qt < 2; qt++) {
            // osum reg r holds full psum for q = qt*16 + quad*4 + r (cols dup)
            float rcp[4] = { 1.f / osum[qt][0], 1.f / osum[qt][1],
                             1.f / osum[qt][2], 1.f / osum[qt][3] };
#pragma unroll
            for (int r = 0; r < 4; r++) {
                int s = q0 + wave * 32 + qt * 16 + quad * 4 + r;   // qh==wave here
#pragma unroll
                for (int dt = 0; dt < 4; dt++) {
                    int d = dt * 16 + l16;
                    Og[((size_t)(b * S_ + s)) * D_ + h * 64 + d] = f2bf(o[qt][dt][r] * rcp[r]);
                }
            }
        }
    }
}

// ---------------------------------------------------------------------------
extern "C" void kernel_launch(void* const* d_in, const int* in_sizes, int n_in,
                              void* d_out, int out_size, void* d_ws, size_t ws_size,
                              hipStream_t stream) {
    const float* hs = (const float*)d_in[0];
    const int* mask = (const int*)d_in[1];
    const float* Wq = (const float*)d_in[2];
    const float* bq = (const float*)d_in[3];
    const float* Wk = (const float*)d_in[4];
    const float* bk = (const float*)d_in[5];
    const float* Wv = (const float*)d_in[6];
    const float* bv = (const float*)d_in[7];
    const float* Wo = (const float*)d_in[8];
    const float* bo = (const float*)d_in[9];
    float* out = (float*)d_out;

    char* ws = (char*)d_ws;
    bf16* hsb  = (bf16*)(ws);                          // 8 MB (4096x1024)
    bf16* wqkv = (bf16*)(ws + ((size_t)8 << 20));      // 6 MB (3072x1024)
    bf16* wob  = (bf16*)(ws + ((size_t)14 << 20));     // 2 MB (1024x1024)
    bf16* Qw   = (bf16*)(ws + ((size_t)16 << 20));     // 8 MB (b,h,s,d)
    bf16* Kw   = (bf16*)(ws + ((size_t)24 << 20));     // 8 MB (b,h,s,d)
    bf16* Vtw  = (bf16*)(ws + ((size_t)32 << 20));     // 8 MB (b,h,d,s)
    bf16* attn = (bf16*)(ws + ((size_t)40 << 20));     // 8 MB (b,s,h*64+d)

    cvt_kernel<<<8192, 256, 0, stream>>>(hs, Wq, Wk, Wv, Wo, hsb, wqkv, wob);
    gemm_bt<<<dim3(32, 24), 256, 0, stream>>>(hsb, wqkv, bq, bk, bv,
                                              Qw, Kw, Vtw);
    attn_kernel<<<dim3(32, 32), 256, 0, stream>>>(Qw, Kw, Vtw, mask, attn);
    gemm_out<<<dim3(32, 16), 256, 0, stream>>>(attn, wob, bo, out);
}